// Round 1
// 163.366 us; speedup vs baseline: 1.0344x; 1.0344x over previous
//
#include <hip/hip_runtime.h>
#include <hip/hip_bf16.h>
#include <hip/hip_fp16.h>
#include <math.h>

// Problem constants
#define B_ 4
#define C_ 256
#define H_ 64
#define W_ 64
#define COMP_ 64
#define K2_ 25
#define HW_ (H_*W_)   // 4096
#define EPS_ 1e-5f
#define WTE_STRIDE 26  // 25 k2 values padded to 26 for 8B-aligned float2 loads

typedef float v2f __attribute__((ext_vector_type(2)));
#define FMA2(a, b, c) __builtin_elementwise_fma((a), (b), (c))

// ---------------------------------------------------------------------------
// Kernel T: weight layout transforms (scalar-load-friendly).
//   wTc[c*64+o]                        = w_comp[o*256+c]
//   wTe[((o*9+q)*4+s2)*26 + k2]        = w_enc[((k2*4+s2)*64+o)*9+q]
// ---------------------------------------------------------------------------
__global__ void k_transpose(const float* __restrict__ w_comp,
                            const float* __restrict__ w_enc,
                            float* __restrict__ wTc,
                            float* __restrict__ wTe) {
    int t = blockIdx.x * 256 + threadIdx.x;
    if (t < COMP_ * C_) {
        int o = t & 63;
        int c = t >> 6;
        wTc[t] = w_comp[o * C_ + c];
    } else {
        int t2 = t - COMP_ * C_;
        if (t2 < 100 * COMP_ * 9) {
            int k2 = t2 % 25;
            int r = t2 / 25;
            int s2 = r & 3; r >>= 2;
            int q = r % 9;
            int o = r / 9;
            wTe[((o * 9 + q) * 4 + s2) * WTE_STRIDE + k2] =
                w_enc[(((k2 * 4 + s2) * COMP_) + o) * 9 + q];
        }
    }
}

// ---------------------------------------------------------------------------
// Kernel A (v2): 1x1 compression (256->64) + BN + SiLU.
// grid (64 px-tiles, B) = 256 blocks, block (64 px, 8 og) = 512 thr = 8 waves.
// Full 64px x 256ch x-tile staged ONCE in LDS (69.6 KB, stride-68 pad:
// 16B-aligned float4 writes, conflict-free b32 broadcast reads).
// Each thread: 8 outputs, full K=256 — no cross-thread reduction, 1 barrier.
// Removes the previous 8x-redundant global x loads.
// ---------------------------------------------------------------------------
__global__ void __launch_bounds__(512)
k_compress(const float* __restrict__ x, const float* __restrict__ wTc,
           const float* __restrict__ gamma, const float* __restrict__ beta,
           const float* __restrict__ mean, const float* __restrict__ var,
           float* __restrict__ act) {
    __shared__ float sx[256 * 68];                 // 69,632 B
    const int tx = threadIdx.x;                    // px
    const int ty = threadIdx.y;                    // og (0..7)
    const int tid = ty * 64 + tx;
    const int ogu = __builtin_amdgcn_readfirstlane(ty);
    const int b = blockIdx.y;
    const int p0 = blockIdx.x * 64;

    const float* xb = x + (size_t)b * C_ * HW_ + p0;
    // stage: 4096 float4s (16 per channel row), 8 per thread, fully coalesced
#pragma unroll
    for (int l = 0; l < 8; ++l) {
        int e = tid + l * 512;                     // 0..4095
        int c = e >> 4;
        int p4 = (e & 15) << 2;
        float4 v4 = *(const float4*)(xb + (size_t)c * HW_ + p4);
        *(float4*)&sx[c * 68 + p4] = v4;
    }
    __syncthreads();

    v2f acc2[4];
#pragma unroll
    for (int k = 0; k < 4; ++k) acc2[k] = (v2f){0.f, 0.f};

#pragma unroll 8
    for (int c = 0; c < 256; ++c) {
        float xv = sx[c * 68 + tx];
        const v2f* w2 = (const v2f*)(wTc + c * COMP_ + ogu * 8);  // uniform -> s_load
        v2f xv2 = (v2f){xv, xv};
#pragma unroll
        for (int k = 0; k < 4; ++k)
            acc2[k] = FMA2(xv2, w2[k], acc2[k]);
    }

#pragma unroll
    for (int k = 0; k < 4; ++k) {
        int o0 = ty * 8 + 2 * k;
#pragma unroll
        for (int h = 0; h < 2; ++h) {
            int o = o0 + h;
            float sv = (h == 0) ? acc2[k].x : acc2[k].y;
            float iv = gamma[o] * rsqrtf(var[o] + EPS_);
            float bn = (sv - mean[o]) * iv + beta[o];
            float sg = 1.f / (1.f + __expf(-bn));
            act[((b * COMP_ + o) * HW_) + p0 + tx] = bn * sg;
        }
    }
}

// ---------------------------------------------------------------------------
// Kernel B: 3x3 encoder conv (64->100) + softmax(25) + fp16 transpose-out.
// grid (64 i, B), block (64 j, 4 s2, 4 og) = 1024 thr.  Packed v2f math.
// Output maskT[b][(i*64+j)*100 + k2*4+s2] in fp16 via in-LDS transpose.
// ---------------------------------------------------------------------------
__global__ void __launch_bounds__(1024)
k_encoder(const float* __restrict__ act, const float* __restrict__ wTe,
          __half* __restrict__ maskT) {
    __shared__ float sact[13312];                  // 53.2 KB
    const int tx = threadIdx.x;                    // j
    const int ty = threadIdx.y;                    // s2
    const int tz = threadIdx.z;                    // og
    const int tid = (tz * 4 + ty) * 64 + tx;
    const int i = blockIdx.x;
    const int b = blockIdx.y;
    const int s2u = __builtin_amdgcn_readfirstlane(ty);
    const int ogu = __builtin_amdgcn_readfirstlane(tz);

    // stage act rows i-1..i+1 with zero halo: [row][o][col(=gj+1)], 3*64*66
    const float* ab = act + (size_t)b * COMP_ * HW_;
    for (int t = tid; t < 3 * COMP_ * 66; t += 1024) {
        int col = t % 66;
        int r = t / 66;
        int o = r & 63;
        int row = r >> 6;
        int gi = i + row - 1;
        int gj = col - 1;
        float v = 0.f;
        if ((unsigned)gi < 64u && (unsigned)gj < 64u)
            v = ab[(o * H_ + gi) * W_ + gj];
        sact[t] = v;
    }
    __syncthreads();

    v2f acc2[13];
#pragma unroll
    for (int k = 0; k < 13; ++k) acc2[k] = (v2f){0.f, 0.f};

#pragma unroll 2
    for (int oi = 0; oi < 16; ++oi) {
        int o = ogu * 16 + oi;                     // uniform
#pragma unroll
        for (int q = 0; q < 9; ++q) {
            const int dy = q / 3, dx = q % 3;
            float a = sact[(dy * COMP_ + o) * 66 + tx + dx];
            const float* wb = wTe + ((o * 9 + q) * 4 + s2u) * WTE_STRIDE;  // uniform
            const v2f* w2 = (const v2f*)wb;
            v2f a2 = (v2f){a, a};
#pragma unroll
            for (int k = 0; k < 12; ++k)
                acc2[k] = FMA2(a2, w2[k], acc2[k]);
            acc2[12].x = fmaf(wb[24], a, acc2[12].x);
        }
    }
    __syncthreads();                               // sact reads done

    v2f* bufA = (v2f*)sact;                        // 3328 v2f
    v2f* bufB = bufA + 3328;                       // 3328 v2f
    const int rix = ty * 64 + tx;                  // 0..255
    if (tz == 1) {
#pragma unroll
        for (int k = 0; k < 13; ++k) bufA[k * 256 + rix] = acc2[k];
    } else if (tz == 2) {
#pragma unroll
        for (int k = 0; k < 13; ++k) bufB[k * 256 + rix] = acc2[k];
    }
    __syncthreads();
    if (tz == 0) {
#pragma unroll
        for (int k = 0; k < 13; ++k) acc2[k] += bufA[k * 256 + rix];
    } else if (tz == 3) {
#pragma unroll
        for (int k = 0; k < 13; ++k) acc2[k] += bufB[k * 256 + rix];
    }
    __syncthreads();
    if (tz == 3) {
#pragma unroll
        for (int k = 0; k < 13; ++k) bufA[k * 256 + rix] = acc2[k];
    }
    __syncthreads();
    float ex[K2_];
    if (tz == 0) {
#pragma unroll
        for (int k = 0; k < 13; ++k) acc2[k] += bufA[k * 256 + rix];

        // softmax over 25 (acc2[12].y is junk — ignored)
        float mx = acc2[12].x;
#pragma unroll
        for (int k = 0; k < 12; ++k) mx = fmaxf(mx, fmaxf(acc2[k].x, acc2[k].y));
        float sum = 0.f;
#pragma unroll
        for (int k = 0; k < 12; ++k) {
            ex[2 * k]     = __expf(acc2[k].x - mx);
            ex[2 * k + 1] = __expf(acc2[k].y - mx);
            sum += ex[2 * k] + ex[2 * k + 1];
        }
        ex[24] = __expf(acc2[12].x - mx);
        sum += ex[24];
        float rs = 1.f / sum;
#pragma unroll
        for (int k = 0; k < K2_; ++k) ex[k] *= rs;
    }
    __syncthreads();                               // bufA reads done before reuse

    __half* st = (__half*)sact;                    // transpose buffer [j][100] fp16
    if (tz == 0) {
#pragma unroll
        for (int k = 0; k < K2_; ++k)
            st[tx * 100 + k * 4 + ty] = __float2half(ex[k]);  // 2-way banks: free
    }
    __syncthreads();

    // coalesced write: maskT[b][(i*64+j)*100 + ch], 800 float4 of halfs
    float4* dst = (float4*)(maskT + ((size_t)b * HW_ + i * 64) * 100);
    const float4* src = (const float4*)st;
    if (tid < 800) dst[tid] = src[tid];
}

// ---------------------------------------------------------------------------
// Kernel C (v2): reassembly + pixel shuffle.
// 1D grid 4096 with bijective XCD swizzle, cc innermost: the 16 cc-blocks of
// one (b,i) run consecutively on ONE XCD (mask row 15/16 L2-hit), successive
// i reuse 4/5 x halo rows in the same L2.
// Staging hoisted: ALL global loads (mask 4xfloat4 + x 1360 ch-quad gathers,
// flattened to 6 predicated slots/thread) issue before any ds_write -> one
// vmcnt latency exposure instead of five.
// ---------------------------------------------------------------------------
__global__ void __launch_bounds__(256)
k_reassemble(const float* __restrict__ x, const __half* __restrict__ maskT,
             float* __restrict__ out) {
    __shared__ __align__(16) __half smask[64 * 100];  // 12.8 KB
    __shared__ __align__(16) float sx[5 * 68 * 20];   // 27.2 KB
    const int tx = threadIdx.x;                    // j
    const int ty = threadIdx.y;                    // ch-quad
    const int tid = ty * 64 + tx;

    const int bid = blockIdx.x;                    // 0..4095
    const int wg  = ((bid & 7) << 9) | (bid >> 3); // XCD-contiguous, bijective
    const int cc = wg & 15;
    const int i  = (wg >> 4) & 63;
    const int b  = wg >> 10;

    // ---- issue mask loads (800 float4 of halfs) ----
    const float4* msrc = (const float4*)(maskT + ((size_t)b * HW_ + i * 64) * 100);
    float4 vm[4];
#pragma unroll
    for (int t = 0; t < 4; ++t) {
        int e = tid + t * 256;
        vm[t] = (e < 800) ? msrc[e] : make_float4(0.f, 0.f, 0.f, 0.f);
    }

    // ---- issue x loads: 1360 channel-quad gathers = 5 rows x 68 cols x 4 q ----
    float4 vx[6];
#pragma unroll
    for (int l = 0; l < 6; ++l) {
        int e = tid + l * 256;                     // 0..1535
        int q = e / 340;                           // ch-quad (valid 0..3)
        int rem = e - q * 340;
        int r = rem / 68;                          // row 0..4
        int col = rem - r * 68;                    // 0..67
        int gi = i + r - 2;
        int gj = col - 2;
        float4 v = make_float4(0.f, 0.f, 0.f, 0.f);
        if (e < 1360 && (unsigned)gi < 64u && (unsigned)gj < 64u) {
            const float* p = x + ((size_t)b * C_ + cc * 16 + q * 4) * HW_ + gi * W_ + gj;
            v.x = p[0];
            v.y = p[HW_];
            v.z = p[2 * HW_];
            v.w = p[3 * HW_];
        }
        vx[l] = v;
    }

    // ---- drain once, write LDS ----
    {
        float4* mdst = (float4*)smask;
#pragma unroll
        for (int t = 0; t < 4; ++t) {
            int e = tid + t * 256;
            if (e < 800) mdst[e] = vm[t];
        }
    }
#pragma unroll
    for (int l = 0; l < 6; ++l) {
        int e = tid + l * 256;
        if (e < 1360) {
            int q = e / 340;
            int rem = e - q * 340;
            int r = rem / 68;
            int col = rem - r * 68;
            *(float4*)&sx[(r * 68 + col) * 20 + q * 4] = vx[l];  // zero-padded halo incl.
        }
    }
    __syncthreads();

    v2f a01[4], a23[4];
#pragma unroll
    for (int cl = 0; cl < 4; ++cl) { a01[cl] = (v2f){0.f, 0.f}; a23[cl] = (v2f){0.f, 0.f}; }

    // prefetch k2=0
    float4 xq = *(const float4*)&sx[(0 * 68 + tx + 0) * 20 + ty * 4];
    __half2 h01 = *(const __half2*)&smask[tx * 100 + 0];
    __half2 h23 = *(const __half2*)&smask[tx * 100 + 2];

#pragma unroll
    for (int k2 = 0; k2 < K2_; ++k2) {
        float4 xq_c = xq;
        __half2 h01_c = h01, h23_c = h23;
        if (k2 < K2_ - 1) {
            const int kn = k2 + 1;
            const int dy = kn / 5, dx = kn % 5;
            xq  = *(const float4*)&sx[(dy * 68 + tx + dx) * 20 + ty * 4];
            h01 = *(const __half2*)&smask[tx * 100 + kn * 4];
            h23 = *(const __half2*)&smask[tx * 100 + kn * 4 + 2];
        }
        float2 f01 = __half22float2(h01_c);
        float2 f23 = __half22float2(h23_c);
        v2f m01 = (v2f){f01.x, f01.y};
        v2f m23 = (v2f){f23.x, f23.y};
        float xc[4] = {xq_c.x, xq_c.y, xq_c.z, xq_c.w};
#pragma unroll
        for (int cl = 0; cl < 4; ++cl) {
            v2f xv2 = (v2f){xc[cl], xc[cl]};
            a01[cl] = FMA2(xv2, m01, a01[cl]);
            a23[cl] = FMA2(xv2, m23, a23[cl]);
        }
    }

#pragma unroll
    for (int cl = 0; cl < 4; ++cl) {
        int c = cc * 16 + ty * 4 + cl;
        float* op = out + (((size_t)(b * C_ + c) * 128 + 2 * i) * 128) + 2 * tx;
        *(float2*)op         = float2{a01[cl].x, a01[cl].y};
        *(float2*)(op + 128) = float2{a23[cl].x, a23[cl].y};
    }
}

// ---------------------------------------------------------------------------
extern "C" void kernel_launch(void* const* d_in, const int* in_sizes, int n_in,
                              void* d_out, int out_size, void* d_ws, size_t ws_size,
                              hipStream_t stream) {
    const float* x       = (const float*)d_in[0];
    const float* w_comp  = (const float*)d_in[1];
    const float* bn_g    = (const float*)d_in[2];
    const float* bn_b    = (const float*)d_in[3];
    const float* bn_m    = (const float*)d_in[4];
    const float* bn_v    = (const float*)d_in[5];
    const float* w_enc   = (const float*)d_in[6];
    float* out = (float*)d_out;

    float* ws    = (float*)d_ws;
    float* wTc   = ws;                               // 16384 floats
    float* wTe   = ws + 16384;                       // 59904 floats (stride 26)
    float* act   = ws + 16384 + 59904;               // 1,048,576 floats
    __half* maskT = (__half*)(act + (size_t)B_ * COMP_ * HW_);  // 1,638,400 halfs

    k_transpose<<<289, 256, 0, stream>>>(w_comp, w_enc, wTc, wTe);
    k_compress<<<dim3(64, B_), dim3(64, 8), 0, stream>>>(x, wTc, bn_g, bn_b, bn_m, bn_v, act);
    k_encoder<<<dim3(64, B_), dim3(64, 4, 4), 0, stream>>>(act, wTe, maskT);
    k_reassemble<<<4096, dim3(64, 4), 0, stream>>>(x, maskT, out);
}